// Round 5
// baseline (485.635 us; speedup 1.0000x reference)
//
#include <hip/hip_runtime.h>

#define DD 256
#define KK 1024
#define HW 4096
#define NROWSZ 65536
#define OUT_Z 16777216
#define OUT_IDX OUT_Z
#define OUT_LOSS (OUT_Z + NROWSZ)

#define MARGIN 2.0e-4f

// ws layout (bytes)
#define WS_ZSQ   0          // float[65536]
#define WS_ESQ   262144     // float[1024]
#define WS_EH    266240     // _Float16[262144] emb in fp16, [k][d]
#define WS_HLIST 790528     // int[65536]
#define WS_HCNT  1052672    // int
#define WS_DONE  1052676    // int
#define WS_LSUM  1052680    // double

typedef _Float16 f16x8 __attribute__((ext_vector_type(8)));
typedef float f32x4 __attribute__((ext_vector_type(4)));
union U16x8 { uint4 u; f16x8 h; };
typedef unsigned long long u64;

static __device__ __forceinline__ u64 umin64(u64 a, u64 b) { return a < b ? a : b; }
static __device__ __forceinline__ u64 umax64(u64 a, u64 b) { return a > b ? a : b; }

// order-preserving float->uint key (handles negatives)
static __device__ __forceinline__ unsigned fkey(float s) {
    unsigned b = __float_as_uint(s);
    unsigned flip = (unsigned)((int)b >> 31) | 0x80000000u;
    return b ^ flip;
}
static __device__ __forceinline__ float funkey(unsigned k) {
    unsigned b = (k & 0x80000000u) ? (k ^ 0x80000000u) : ~k;
    return __uint_as_float(b);
}

// ---------------- prep: zsq (numpy pairwise-8 exact), esq, eh fp16, zero scalars ----
__global__ void vq_prep(const float* __restrict__ z, const float* __restrict__ emb,
                        float* __restrict__ zsq, float* __restrict__ esq,
                        uint2* __restrict__ eh2, int* __restrict__ hcnt,
                        int* __restrict__ done, double* __restrict__ lsum)
{
    const int bid = blockIdx.x;
    const int t = threadIdx.x;
    if (bid == 0 && t == 0) { *hcnt = 0; *done = 0; *lsum = 0.0; }

    if (bid < 256) {
        // zsq: numpy pairwise_sum exact emulation (two 128-blocks of 8 accumulators)
        int n = bid * 256 + t;
        const float* p = z + (size_t)(n >> 12) * (DD * HW) + (n & (HW - 1));
        float blk[2];
#pragma unroll
        for (int b2 = 0; b2 < 2; ++b2) {
            const int p0 = b2 * 128;
            float r[8];
#pragma unroll
            for (int j = 0; j < 8; ++j) {
                float v = p[(size_t)(p0 + j) * HW];
                r[j] = __fmul_rn(v, v);
            }
            for (int i = 8; i < 128; i += 8) {
#pragma unroll
                for (int j = 0; j < 8; ++j) {
                    float v = p[(size_t)(p0 + i + j) * HW];
                    r[j] = __fadd_rn(r[j], __fmul_rn(v, v));
                }
            }
            blk[b2] = __fadd_rn(__fadd_rn(__fadd_rn(r[0], r[1]), __fadd_rn(r[2], r[3])),
                                __fadd_rn(__fadd_rn(r[4], r[5]), __fadd_rn(r[6], r[7])));
        }
        zsq[n] = __fadd_rn(blk[0], blk[1]);
    } else if (bid < 260) {
        int k = (bid - 256) * 256 + t;
        const float* e = emb + (size_t)k * DD;
        float blk[2];
#pragma unroll
        for (int b2 = 0; b2 < 2; ++b2) {
            const float* p = e + b2 * 128;
            float r[8];
#pragma unroll
            for (int j = 0; j < 8; ++j) r[j] = __fmul_rn(p[j], p[j]);
            for (int i = 8; i < 128; i += 8) {
#pragma unroll
                for (int j = 0; j < 8; ++j)
                    r[j] = __fadd_rn(r[j], __fmul_rn(p[i + j], p[i + j]));
            }
            blk[b2] = __fadd_rn(__fadd_rn(__fadd_rn(r[0], r[1]), __fadd_rn(r[2], r[3])),
                                __fadd_rn(__fadd_rn(r[4], r[5]), __fadd_rn(r[6], r[7])));
        }
        esq[k] = __fadd_rn(blk[0], blk[1]);
    } else {
        // eh: emb -> fp16, 16 blocks x 256 thr x 16 iters over 65536 float4s
        int tid = (bid - 260) * 256 + t;
        const float4* e4 = (const float4*)emb;
#pragma unroll
        for (int i = 0; i < 16; ++i) {
            int idx = i * 4096 + tid;
            float4 v = e4[idx];
            _Float16 h0 = (_Float16)v.x, h1 = (_Float16)v.y;
            _Float16 h2 = (_Float16)v.z, h3 = (_Float16)v.w;
            uint2 o;
            o.x = (unsigned)__builtin_bit_cast(unsigned short, h0)
                | ((unsigned)__builtin_bit_cast(unsigned short, h1) << 16);
            o.y = (unsigned)__builtin_bit_cast(unsigned short, h2)
                | ((unsigned)__builtin_bit_cast(unsigned short, h3) << 16);
            eh2[idx] = o;
        }
    }
}

// ---------------- score: persistent-A fp16 MFMA, B from L2, fused margin/route ------
// 1024 blocks x 64 rows; 4 waves, each wave: 64 rows x 64 codes per 256-code chunk.
__launch_bounds__(256, 2)
__global__ void vq_score(const float* __restrict__ z, const _Float16* __restrict__ eh,
                         const float* __restrict__ esq, float* __restrict__ out,
                         int* __restrict__ hlist, int* __restrict__ hcnt)
{
    __shared__ __align__(16) unsigned short ah[64 * 264];   // [row][d], pitch 264 halves
    __shared__ u64 cand[64][4][2];

    const int t = threadIdx.x;
    const int lane = t & 63;
    const int w = t >> 6;
    const int col = lane & 15;
    const int quad = lane >> 4;

    const int n0 = blockIdx.x * 64;
    const int b = n0 >> 12;
    const int hw0 = n0 & (HW - 1);
    const float* zbase = z + (size_t)b * DD * HW;

    // ---- stage A once: z fp32 -> fp16 -> LDS [row][d]
    {
        const int r = t & 63, dg = t >> 6;
        const float* src = zbase + hw0 + r + (size_t)(dg * 64) * HW;
        unsigned short* dst = &ah[r * 264 + dg * 64];
#pragma unroll 8
        for (int i = 0; i < 64; ++i) {
            float v = src[(size_t)i * HW];
            _Float16 h = (_Float16)v;
            dst[i] = __builtin_bit_cast(unsigned short, h);
        }
    }
    __syncthreads();

    // per-lane running top2 for 16 (nt,r) rows
    u64 m1[16], m2[16];
#pragma unroll
    for (int i = 0; i < 16; ++i) { m1[i] = ~0ull; m2[i] = ~0ull; }

    for (int kt = 0; kt < 4; ++kt) {
        const int cb = kt * 256 + w * 64;            // this wave's 64-code base
        float eqv[4];
        const uint4* bptr[4];
#pragma unroll
        for (int ct = 0; ct < 4; ++ct) {
            int code = cb + ct * 16 + col;
            eqv[ct] = esq[code];
            bptr[ct] = (const uint4*)(eh + (size_t)code * 256 + quad * 8);
        }

        f32x4 acc[4][4];
#pragma unroll
        for (int nt = 0; nt < 4; ++nt)
#pragma unroll
            for (int ct = 0; ct < 4; ++ct) acc[nt][ct] = (f32x4)0.0f;

#pragma unroll
        for (int ds = 0; ds < 8; ++ds) {
            U16x8 bf[4];
#pragma unroll
            for (int ct = 0; ct < 4; ++ct) bf[ct].u = bptr[ct][ds * 4];
            U16x8 af[4];
#pragma unroll
            for (int nt = 0; nt < 4; ++nt)
                af[nt].u = *(const uint4*)&ah[(nt * 16 + col) * 264 + ds * 32 + quad * 8];
#pragma unroll
            for (int nt = 0; nt < 4; ++nt)
#pragma unroll
                for (int ct = 0; ct < 4; ++ct)
                    acc[nt][ct] = __builtin_amdgcn_mfma_f32_16x16x32_f16(
                        af[nt].h, bf[ct].h, acc[nt][ct], 0, 0, 0);
        }

        // fold: s' = esq - 2*dot (zsq omitted: constant per row)
#pragma unroll
        for (int nt = 0; nt < 4; ++nt)
#pragma unroll
            for (int r = 0; r < 4; ++r) {
                int mi = nt * 4 + r;
                u64 a = m1[mi], bb = m2[mi];
#pragma unroll
                for (int ct = 0; ct < 4; ++ct) {
                    float s = __fsub_rn(eqv[ct], __fmul_rn(2.0f, acc[nt][ct][r]));
                    u64 p = ((u64)fkey(s) << 32) | (unsigned)(cb + ct * 16 + col);
                    u64 mx = umax64(a, p);
                    a = umin64(a, p);
                    bb = umin64(bb, mx);
                }
                m1[mi] = a; m2[mi] = bb;
            }
    }

    // cross-col (16-lane) fold
#pragma unroll
    for (int mi = 0; mi < 16; ++mi) {
        u64 a = m1[mi], bb = m2[mi];
#pragma unroll
        for (int off = 1; off < 16; off <<= 1) {
            u64 o1 = __shfl_xor(a, off, 16);
            u64 o2 = __shfl_xor(bb, off, 16);
            u64 mx = umax64(a, o1);
            a = umin64(a, o1);
            bb = umin64(umin64(bb, o2), mx);
        }
        if (col == 0) {
            int row = (mi >> 2) * 16 + quad * 4 + (mi & 3);
            cand[row][w][0] = a;
            cand[row][w][1] = bb;
        }
    }
    __syncthreads();

    if (t < 64) {
        u64 a = cand[t][0][0], bb = cand[t][0][1];
#pragma unroll
        for (int ww = 1; ww < 4; ++ww) {
            u64 v1 = cand[t][ww][0], v2 = cand[t][ww][1];
            u64 mx = umax64(a, v1);
            a = umin64(a, v1);
            bb = umin64(umin64(bb, v2), mx);
        }
        float s1 = funkey((unsigned)(a >> 32));
        float s2 = funkey((unsigned)(bb >> 32));
        int k1 = (int)(a & 0xffffffffu);
        int row = n0 + t;
        if (s2 - s1 > MARGIN) {
            out[OUT_IDX + row] = (float)k1;
        } else {
            int pos = atomicAdd(hcnt, 1);
            hlist[pos] = row;
        }
    }
}

// ---------------- hard: bit-exact fp32 rescan of all 1024 codes for hard rows ------
__launch_bounds__(256)
__global__ void vq_hard(const float* __restrict__ z, const float* __restrict__ emb,
                        const float* __restrict__ zsq, const float* __restrict__ esq,
                        const int* __restrict__ hlist, const int* __restrict__ hcnt,
                        float* __restrict__ out)
{
    __shared__ float e_lds[1024 * 12];
    __shared__ float z_lds[8][8];
    __shared__ float zq_s[8];
    __shared__ int rows_s[8];
    __shared__ u64 red[4][8];

    const int t = threadIdx.x;
    const int lane = t & 63;
    const int w = t >> 6;
    const int count = *hcnt;

    for (int g = blockIdx.x; g * 8 < count; g += gridDim.x) {
        if (t < 8) {
            int idx = g * 8 + t;
            int r = (idx < count) ? hlist[idx] : -1;
            rows_s[t] = r;
            int rr = (r < 0) ? 0 : r;
            zq_s[t] = zsq[rr];
        }
        __syncthreads();

        float acc_[8][4];
#pragma unroll
        for (int j = 0; j < 8; ++j)
#pragma unroll
            for (int kk = 0; kk < 4; ++kk) acc_[j][kk] = 0.0f;

        for (int dc = 0; dc < 32; ++dc) {
            const int d0 = dc * 8;
            __syncthreads();
#pragma unroll
            for (int s = 0; s < 4; ++s) {
                int k = s * 256 + t;
                const float* ep = emb + (size_t)k * DD + d0;
                float4 v0 = *(const float4*)ep;
                float4 v1 = *(const float4*)(ep + 4);
                *(float4*)&e_lds[k * 12] = v0;
                *(float4*)&e_lds[k * 12 + 4] = v1;
            }
            if (t < 64) {
                int j = t >> 3, dd = t & 7;
                int r = rows_s[j];
                int rr = (r < 0) ? 0 : r;
                z_lds[j][dd] = z[(size_t)(rr >> 12) * DD * HW + (size_t)(d0 + dd) * HW + (rr & (HW - 1))];
            }
            __syncthreads();
#pragma unroll
            for (int kk = 0; kk < 4; ++kk) {
                int k = kk * 256 + t;
                float4 e0 = *(const float4*)&e_lds[k * 12];
                float4 e1 = *(const float4*)&e_lds[k * 12 + 4];
#pragma unroll
                for (int j = 0; j < 8; ++j) {
                    float4 z0 = *(const float4*)&z_lds[j][0];
                    float4 z1 = *(const float4*)&z_lds[j][4];
                    float a = acc_[j][kk];
                    a = fmaf(z0.x, e0.x, a);
                    a = fmaf(z0.y, e0.y, a);
                    a = fmaf(z0.z, e0.z, a);
                    a = fmaf(z0.w, e0.w, a);
                    a = fmaf(z1.x, e1.x, a);
                    a = fmaf(z1.y, e1.y, a);
                    a = fmaf(z1.z, e1.z, a);
                    a = fmaf(z1.w, e1.w, a);
                    acc_[j][kk] = a;
                }
            }
        }

        float eqv[4];
#pragma unroll
        for (int kk = 0; kk < 4; ++kk) eqv[kk] = esq[kk * 256 + t];

#pragma unroll
        for (int j = 0; j < 8; ++j) {
            u64 m = ~0ull;
#pragma unroll
            for (int kk = 0; kk < 4; ++kk) {
                int k = kk * 256 + t;
                float s = __fsub_rn(__fadd_rn(zq_s[j], eqv[kk]), __fmul_rn(2.0f, acc_[j][kk]));
                u64 p = ((u64)__float_as_uint(s) << 32) | (unsigned)k;  // s >= 0 here
                m = umin64(m, p);
            }
#pragma unroll
            for (int off = 1; off < 64; off <<= 1)
                m = umin64(m, __shfl_xor(m, off, 64));
            if (lane == 0) red[w][j] = m;
        }
        __syncthreads();
        if (t < 8) {
            u64 m = umin64(umin64(red[0][t], red[1][t]), umin64(red[2][t], red[3][t]));
            int r = rows_s[t];
            if (r >= 0) out[OUT_IDX + r] = (float)(int)(m & 0xffffffffu);
        }
        __syncthreads();
    }
}

// ---------------- finish: z_q scatter + loss, fused final via ticket ----------------
__global__ void vq_finish(const float* __restrict__ z, const float* __restrict__ emb,
                          float* __restrict__ out, double* __restrict__ lsum,
                          int* __restrict__ done)
{
    __shared__ int idxs[64];
    __shared__ float wsum[4];

    const int t = threadIdx.x;
    const int n0 = blockIdx.x * 64;
    const int b = n0 >> 12;
    const int hw0 = n0 & (HW - 1);

    if (t < 64) idxs[t] = (int)out[OUT_IDX + n0 + t];
    __syncthreads();

    const int n = t & 63;
    const int dg = t >> 6;
    const float* erow = emb + (size_t)idxs[n] * DD;
    const float* zc = z + (size_t)b * DD * HW + hw0 + n;
    float* oc = out + (size_t)b * DD * HW + hw0 + n;
    float lacc = 0.f;
#pragma unroll 4
    for (int dd = 0; dd < 64; ++dd) {
        int d = dg * 64 + dd;
        float e = erow[d];
        float zv = zc[(size_t)d * HW];
        oc[(size_t)d * HW] = e;
        float df = e - zv;
        lacc = fmaf(df, df, lacc);
    }
#pragma unroll
    for (int off = 32; off > 0; off >>= 1) lacc += __shfl_down(lacc, off, 64);
    if ((t & 63) == 0) wsum[t >> 6] = lacc;
    __syncthreads();
    if (t == 0) {
        double tot = (double)wsum[0] + (double)wsum[1] + (double)wsum[2] + (double)wsum[3];
        double prev = atomicAdd(lsum, tot);
        __threadfence();
        int ticket = atomicAdd(done, 1);
        if (ticket == (int)gridDim.x - 1) {
            out[OUT_LOSS] = (float)(0.25 * ((prev + tot) / (double)OUT_Z));
        }
    }
}

extern "C" void kernel_launch(void* const* d_in, const int* in_sizes, int n_in,
                              void* d_out, int out_size, void* d_ws, size_t ws_size,
                              hipStream_t stream)
{
    const float* z = (const float*)d_in[0];
    const float* emb = (const float*)d_in[1];
    float* out = (float*)d_out;
    char* w = (char*)d_ws;

    float* zsq = (float*)(w + WS_ZSQ);
    float* esq = (float*)(w + WS_ESQ);
    _Float16* eh = (_Float16*)(w + WS_EH);
    uint2* eh2 = (uint2*)(w + WS_EH);
    int* hlist = (int*)(w + WS_HLIST);
    int* hcnt = (int*)(w + WS_HCNT);
    int* done = (int*)(w + WS_DONE);
    double* lsum = (double*)(w + WS_LSUM);

    vq_prep<<<dim3(276), dim3(256), 0, stream>>>(z, emb, zsq, esq, eh2, hcnt, done, lsum);
    vq_score<<<dim3(1024), dim3(256), 0, stream>>>(z, eh, esq, out, hlist, hcnt);
    vq_hard<<<dim3(512), dim3(256), 0, stream>>>(z, emb, zsq, esq, hlist, hcnt, out);
    vq_finish<<<dim3(1024), dim3(256), 0, stream>>>(z, emb, out, lsum, done);
}

// Round 6
// 340.233 us; speedup vs baseline: 1.4274x; 1.4274x over previous
//
#include <hip/hip_runtime.h>

#define DD 256
#define KK 1024
#define HW 4096
#define NROWSZ 65536
#define OUT_Z 16777216
#define OUT_IDX OUT_Z
#define OUT_LOSS (OUT_Z + NROWSZ)

#define MARGIN 3.0e-4f

// ws layout (bytes)
#define WS_ESQ   0          // float[1024]
#define WS_EH    4096       // _Float16[262144] emb fp16 [k][d]
#define WS_HLIST 528384     // int[65536]
#define WS_HCNT  790528     // int
#define WS_LSUM  790536     // double

typedef _Float16 f16x8 __attribute__((ext_vector_type(8)));
typedef float f32x4 __attribute__((ext_vector_type(4)));
union U16x8 { uint4 u; f16x8 h; };
typedef unsigned long long u64;

static __device__ __forceinline__ u64 umin64(u64 a, u64 b) { return a < b ? a : b; }
static __device__ __forceinline__ unsigned fkey(float s) {
    unsigned b = __float_as_uint(s);
    unsigned flip = (unsigned)((int)b >> 31) | 0x80000000u;
    return b ^ flip;
}
static __device__ __forceinline__ float funkey(unsigned k) {
    unsigned b = (k & 0x80000000u) ? (k ^ 0x80000000u) : ~k;
    return __uint_as_float(b);
}
static __device__ __forceinline__ unsigned pk16(float a, float b) {
    _Float16 ha = (_Float16)a, hb = (_Float16)b;
    return (unsigned)__builtin_bit_cast(unsigned short, ha)
         | ((unsigned)__builtin_bit_cast(unsigned short, hb) << 16);
}

// ---------------- prep: esq (numpy pairwise-8 exact), eh fp16, init scalars --------
__global__ void vq_prep(const float* __restrict__ emb, float* __restrict__ esq,
                        uint2* __restrict__ eh2, int* __restrict__ hcnt,
                        double* __restrict__ lsum)
{
    const int bid = blockIdx.x;
    const int t = threadIdx.x;
    if (bid == 0 && t == 0) { *hcnt = 0; *lsum = 0.0; }

    if (bid < 4) {
        int k = bid * 256 + t;
        const float* e = emb + (size_t)k * DD;
        float blk[2];
#pragma unroll
        for (int b2 = 0; b2 < 2; ++b2) {
            const float* p = e + b2 * 128;
            float r[8];
#pragma unroll
            for (int j = 0; j < 8; ++j) r[j] = __fmul_rn(p[j], p[j]);
            for (int i = 8; i < 128; i += 8) {
#pragma unroll
                for (int j = 0; j < 8; ++j)
                    r[j] = __fadd_rn(r[j], __fmul_rn(p[i + j], p[i + j]));
            }
            blk[b2] = __fadd_rn(__fadd_rn(__fadd_rn(r[0], r[1]), __fadd_rn(r[2], r[3])),
                                __fadd_rn(__fadd_rn(r[4], r[5]), __fadd_rn(r[6], r[7])));
        }
        esq[k] = __fadd_rn(blk[0], blk[1]);
    } else {
        int tid = (bid - 4) * 256 + t;
        const float4* e4 = (const float4*)emb;
#pragma unroll
        for (int i = 0; i < 16; ++i) {
            int idx = i * 4096 + tid;
            float4 v = e4[idx];
            eh2[idx] = make_uint2(pk16(v.x, v.y), pk16(v.z, v.w));
        }
    }
}

// ---------------- score: A-in-registers MFMA + fused scatter/loss for certain rows --
__launch_bounds__(256, 2)
__global__ void vq_score(const float* __restrict__ z, const float* __restrict__ emb,
                         const _Float16* __restrict__ eh, const float* __restrict__ esq,
                         float* __restrict__ out, int* __restrict__ hlist,
                         int* __restrict__ hcnt, double* __restrict__ lsum)
{
    __shared__ __align__(16) float zf[64 * 264];   // 67.6 KB, z fp32 [row][d]
    __shared__ uint2 cand[64][4];
    __shared__ int idxs[64];
    __shared__ float wsum[4];

    const int t = threadIdx.x;
    const int lane = t & 63;
    const int w = t >> 6;
    const int col = lane & 15;
    const int quad = lane >> 4;

    const int n0 = blockIdx.x * 64;
    const int b = n0 >> 12;
    const int hw0 = n0 & (HW - 1);
    const float* zbase = z + (size_t)b * DD * HW;

    // ---- stage z fp32 -> LDS (coalesced global reads, float4 LDS stores)
    {
        const int r = t & 63, dg = t >> 6;
        const float* src = zbase + hw0 + r + (size_t)(dg * 64) * HW;
        float* dst = &zf[r * 264 + dg * 64];
#pragma unroll 4
        for (int i = 0; i < 16; ++i) {
            float4 v;
            v.x = src[(size_t)(4 * i + 0) * HW];
            v.y = src[(size_t)(4 * i + 1) * HW];
            v.z = src[(size_t)(4 * i + 2) * HW];
            v.w = src[(size_t)(4 * i + 3) * HW];
            *(float4*)&dst[i * 4] = v;
        }
    }
    __syncthreads();

    // ---- A-fragments into registers (fp16, RNE), 128 VGPRs
    U16x8 af[4][8];
#pragma unroll
    for (int nt = 0; nt < 4; ++nt)
#pragma unroll
        for (int ds = 0; ds < 8; ++ds) {
            const float* p = &zf[(nt * 16 + col) * 264 + ds * 32 + quad * 8];
            float4 x0 = *(const float4*)p;
            float4 x1 = *(const float4*)(p + 4);
            af[nt][ds].u = make_uint4(pk16(x0.x, x0.y), pk16(x0.z, x0.w),
                                      pk16(x1.x, x1.y), pk16(x1.z, x1.w));
        }

    // ---- main loop: this wave scans codes [w*256, w*256+256)
    unsigned t1[16], t2[16];
#pragma unroll
    for (int i = 0; i < 16; ++i) { t1[i] = 0xFFFFFFFFu; t2[i] = 0xFFFFFFFFu; }

    const uint4* ehq = (const uint4*)eh;
    const int cbase = w * 256;
    for (int ct = 0; ct < 16; ++ct) {
        const int code = cbase + ct * 16 + col;
        const float eq = esq[code];
        const uint4* bp = ehq + (size_t)code * 32 + quad;
        f32x4 acc[4];
#pragma unroll
        for (int nt = 0; nt < 4; ++nt) acc[nt] = (f32x4)0.0f;
#pragma unroll
        for (int ds = 0; ds < 8; ++ds) {
            U16x8 bf;
            bf.u = bp[ds * 4];
#pragma unroll
            for (int nt = 0; nt < 4; ++nt)
                acc[nt] = __builtin_amdgcn_mfma_f32_16x16x32_f16(af[nt][ds].h, bf.h,
                                                                 acc[nt], 0, 0, 0);
        }
#pragma unroll
        for (int nt = 0; nt < 4; ++nt)
#pragma unroll
            for (int r = 0; r < 4; ++r) {
                float s = __fsub_rn(eq, __fmul_rn(2.0f, acc[nt][r]));
                unsigned key = (fkey(s) & 0xFFFFFC00u) | (unsigned)code;
                int mi = nt * 4 + r;
                unsigned mx = max(t1[mi], key);
                t1[mi] = min(t1[mi], key);
                t2[mi] = min(t2[mi], mx);
            }
    }

    // ---- cross-col (16-lane) top2 merge
#pragma unroll
    for (int mi = 0; mi < 16; ++mi) {
        unsigned a = t1[mi], bb = t2[mi];
#pragma unroll
        for (int off = 1; off < 16; off <<= 1) {
            unsigned o1 = __shfl_xor(a, off, 16);
            unsigned o2 = __shfl_xor(bb, off, 16);
            unsigned mx = max(a, o1);
            a = min(a, o1);
            bb = min(min(bb, o2), mx);
        }
        if (col == 0) {
            int row = (mi >> 2) * 16 + quad * 4 + (mi & 3);
            cand[row][w] = make_uint2(a, bb);
        }
    }
    __syncthreads();

    // ---- cross-wave merge + margin routing
    if (t < 64) {
        uint2 c0 = cand[t][0];
        unsigned a = c0.x, bb = c0.y;
#pragma unroll
        for (int ww = 1; ww < 4; ++ww) {
            uint2 c = cand[t][ww];
            unsigned mx = max(a, c.x);
            a = min(a, c.x);
            bb = min(min(bb, c.y), mx);
        }
        float s1 = funkey(a & 0xFFFFFC00u);
        float s2 = funkey(bb & 0xFFFFFC00u);
        int k1 = (int)(a & 1023u);
        if (__fsub_rn(s2, s1) > MARGIN) {
            idxs[t] = k1;
            out[OUT_IDX + n0 + t] = (float)k1;
        } else {
            idxs[t] = -1;
            int pos = atomicAdd(hcnt, 1);
            hlist[pos] = n0 + t;
        }
    }
    __syncthreads();

    // ---- fused scatter + loss for certain rows (z exact from LDS)
    {
        const int rr = t & 63;
        const int dg = t >> 6;
        int idx = idxs[rr];
        float lacc = 0.f;
        if (idx >= 0) {
            const float* erow = emb + (size_t)idx * DD;
            const float* zrow = &zf[rr * 264];
            float* oc = out + (size_t)b * DD * HW + hw0 + rr;
#pragma unroll 4
            for (int dd = 0; dd < 64; ++dd) {
                int d = dg * 64 + dd;
                float e = erow[d];
                float zv = zrow[d];
                oc[(size_t)d * HW] = e;
                float df = e - zv;
                lacc = fmaf(df, df, lacc);
            }
        }
#pragma unroll
        for (int off = 32; off > 0; off >>= 1) lacc += __shfl_down(lacc, off, 64);
        if (lane == 0) wsum[w] = lacc;
    }
    __syncthreads();
    if (t == 0) {
        double tot = (double)wsum[0] + (double)wsum[1] + (double)wsum[2] + (double)wsum[3];
        atomicAdd(lsum, tot);
    }
}

// ---------------- hard: bit-exact rescan (inline zsq) + scatter + loss -------------
__launch_bounds__(256)
__global__ void vq_hard(const float* __restrict__ z, const float* __restrict__ emb,
                        const float* __restrict__ esq, const int* __restrict__ hlist,
                        const int* __restrict__ hcnt, float* __restrict__ out,
                        double* __restrict__ lsum)
{
    __shared__ float e_lds[1024 * 12];
    __shared__ float z_lds[8][8];
    __shared__ float zq_s[8];
    __shared__ int rows_s[8];
    __shared__ int idx_s[8];
    __shared__ u64 red[4][8];
    __shared__ float chains[8][16];
    __shared__ float wsum[4];

    const int t = threadIdx.x;
    const int lane = t & 63;
    const int w = t >> 6;
    const int count = *hcnt;
    float lacc = 0.f;

    for (int g = blockIdx.x; g * 8 < count; g += gridDim.x) {
        __syncthreads();
        if (t < 8) {
            int idx = g * 8 + t;
            rows_s[t] = (idx < count) ? hlist[idx] : -1;
        }
        __syncthreads();
        // zsq inline, bit-exact numpy pairwise-8: 8 rows x 16 chains x 16 elems
        if (t < 128) {
            int j = t >> 4, c = t & 15, b2 = c >> 3, jj = c & 7;
            int r = rows_s[j];
            int rrow = (r < 0) ? 0 : r;
            const float* p = z + (size_t)(rrow >> 12) * (DD * HW) + (rrow & (HW - 1));
            int base = b2 * 128 + jj;
            float v = p[(size_t)base * HW];
            float acc = __fmul_rn(v, v);
            for (int i = 1; i < 16; ++i) {
                float u = p[(size_t)(base + i * 8) * HW];
                acc = __fadd_rn(acc, __fmul_rn(u, u));
            }
            chains[j][c] = acc;
        }
        __syncthreads();
        if (t < 8) {
            const float* c = chains[t];
            float b0 = __fadd_rn(__fadd_rn(__fadd_rn(c[0], c[1]), __fadd_rn(c[2], c[3])),
                                 __fadd_rn(__fadd_rn(c[4], c[5]), __fadd_rn(c[6], c[7])));
            float b1 = __fadd_rn(__fadd_rn(__fadd_rn(c[8], c[9]), __fadd_rn(c[10], c[11])),
                                 __fadd_rn(__fadd_rn(c[12], c[13]), __fadd_rn(c[14], c[15])));
            zq_s[t] = __fadd_rn(b0, b1);
        }

        float acc_[8][4];
#pragma unroll
        for (int j = 0; j < 8; ++j)
#pragma unroll
            for (int kk = 0; kk < 4; ++kk) acc_[j][kk] = 0.0f;

        for (int dc = 0; dc < 32; ++dc) {
            const int d0 = dc * 8;
            __syncthreads();
#pragma unroll
            for (int s = 0; s < 4; ++s) {
                int k = s * 256 + t;
                const float* ep = emb + (size_t)k * DD + d0;
                float4 v0 = *(const float4*)ep;
                float4 v1 = *(const float4*)(ep + 4);
                *(float4*)&e_lds[k * 12] = v0;
                *(float4*)&e_lds[k * 12 + 4] = v1;
            }
            if (t < 64) {
                int j = t >> 3, dd = t & 7;
                int r = rows_s[j];
                int rr = (r < 0) ? 0 : r;
                z_lds[j][dd] = z[(size_t)(rr >> 12) * DD * HW + (size_t)(d0 + dd) * HW + (rr & (HW - 1))];
            }
            __syncthreads();
#pragma unroll
            for (int kk = 0; kk < 4; ++kk) {
                int k = kk * 256 + t;
                float4 e0 = *(const float4*)&e_lds[k * 12];
                float4 e1 = *(const float4*)&e_lds[k * 12 + 4];
#pragma unroll
                for (int j = 0; j < 8; ++j) {
                    float4 z0 = *(const float4*)&z_lds[j][0];
                    float4 z1 = *(const float4*)&z_lds[j][4];
                    float a = acc_[j][kk];
                    a = fmaf(z0.x, e0.x, a);
                    a = fmaf(z0.y, e0.y, a);
                    a = fmaf(z0.z, e0.z, a);
                    a = fmaf(z0.w, e0.w, a);
                    a = fmaf(z1.x, e1.x, a);
                    a = fmaf(z1.y, e1.y, a);
                    a = fmaf(z1.z, e1.z, a);
                    a = fmaf(z1.w, e1.w, a);
                    acc_[j][kk] = a;
                }
            }
        }

        float eqv[4];
#pragma unroll
        for (int kk = 0; kk < 4; ++kk) eqv[kk] = esq[kk * 256 + t];

#pragma unroll
        for (int j = 0; j < 8; ++j) {
            u64 m = ~0ull;
#pragma unroll
            for (int kk = 0; kk < 4; ++kk) {
                int k = kk * 256 + t;
                float s = __fsub_rn(__fadd_rn(zq_s[j], eqv[kk]), __fmul_rn(2.0f, acc_[j][kk]));
                u64 p = ((u64)__float_as_uint(s) << 32) | (unsigned)k;  // s >= 0
                m = umin64(m, p);
            }
#pragma unroll
            for (int off = 1; off < 64; off <<= 1)
                m = umin64(m, __shfl_xor(m, off, 64));
            if (lane == 0) red[w][j] = m;
        }
        __syncthreads();
        if (t < 8) {
            u64 m = umin64(umin64(red[0][t], red[1][t]), umin64(red[2][t], red[3][t]));
            int ki = (int)(m & 0xffffffffu);
            idx_s[t] = ki;
            int r = rows_s[t];
            if (r >= 0) out[OUT_IDX + r] = (float)ki;
        }
        __syncthreads();
        // scatter + loss for these 8 rows
        for (int p = t; p < 2048; p += 256) {
            int j = p >> 8, d = p & 255;
            int r = rows_s[j];
            if (r >= 0) {
                float e = emb[(size_t)idx_s[j] * DD + d];
                size_t off = (size_t)(r >> 12) * (DD * HW) + (size_t)d * HW + (r & (HW - 1));
                float zv = z[off];
                out[off] = e;
                float df = e - zv;
                lacc = fmaf(df, df, lacc);
            }
        }
    }

#pragma unroll
    for (int off = 32; off > 0; off >>= 1) lacc += __shfl_down(lacc, off, 64);
    if (lane == 0) wsum[w] = lacc;
    __syncthreads();
    if (t == 0) {
        double tot = (double)wsum[0] + (double)wsum[1] + (double)wsum[2] + (double)wsum[3];
        if (tot != 0.0) atomicAdd(lsum, tot);
    }
}

__global__ void vq_final(const double* __restrict__ lsum, float* __restrict__ out)
{
    out[OUT_LOSS] = (float)(0.25 * (lsum[0] / (double)OUT_Z));
}

extern "C" void kernel_launch(void* const* d_in, const int* in_sizes, int n_in,
                              void* d_out, int out_size, void* d_ws, size_t ws_size,
                              hipStream_t stream)
{
    const float* z = (const float*)d_in[0];
    const float* emb = (const float*)d_in[1];
    float* out = (float*)d_out;
    char* w = (char*)d_ws;

    float* esq = (float*)(w + WS_ESQ);
    _Float16* eh = (_Float16*)(w + WS_EH);
    uint2* eh2 = (uint2*)(w + WS_EH);
    int* hlist = (int*)(w + WS_HLIST);
    int* hcnt = (int*)(w + WS_HCNT);
    double* lsum = (double*)(w + WS_LSUM);

    vq_prep<<<dim3(20), dim3(256), 0, stream>>>(emb, esq, eh2, hcnt, lsum);
    vq_score<<<dim3(1024), dim3(256), 0, stream>>>(z, emb, eh, esq, out, hlist, hcnt, lsum);
    vq_hard<<<dim3(512), dim3(256), 0, stream>>>(z, emb, esq, hlist, hcnt, out, lsum);
    vq_final<<<dim3(1), dim3(1), 0, stream>>>(lsum, out);
}